// Round 12
// baseline (81.169 us; speedup 1.0000x reference)
//
#include <hip/hip_runtime.h>

// StructuredMAPLoss: B=1024 rows, C=128 classes.
// out[0] = loss (mean over classes), out[1 + i*C + c] = ranking[i][c].
// One block (128 threads, 8 elements/thread) per class.
// 32-bit sort keys: key = (kw & ~3) | f, invalid -> 0xFFFFFFFC (sorts last).
// Bitonic sort: j<=4 in-register, j=8..256 shfl_xor (lane dist 1..32),
// j=512 via ONE LDS exchange. 4 barriers total, all 2-wave.
// r-histogram (2048 bins) for the pairwise score terms; per-wave atomic epilogue.

constexpr int Bn = 1024;
constexpr int Cn = 128;
constexpr int TPB = 128;
constexpr int E = 8;
constexpr int NBINS = 2048;
constexpr int HPT = NBINS / TPB;   // 16 hist bins per thread
constexpr int ROFF = 3072;         // bin = (r + ROFF) >> 1 ; valid r in [-3071, 1023]

__device__ __forceinline__ unsigned long long pk3(int ff) {
    return (ff != 0 ? 1ull : 0ull) + (ff == 2 ? (1ull << 21) : 0ull) + (ff == 1 ? (1ull << 42) : 0ull);
}

__global__ __launch_bounds__(TPB) void map_loss_kernel(
    const float* __restrict__ x,
    const int* __restrict__ tgt,
    const void* __restrict__ maskraw,
    float* __restrict__ out)
{
    __shared__ unsigned int kbuf[Bn];                // 4 KB (single use)
    __shared__ unsigned int hist[NBINS];             // 8 KB
    __shared__ unsigned long long wtot[2];
    __shared__ unsigned int hwt[2];
    __shared__ int iwt[2];

    const int c    = blockIdx.x;
    const int tid  = threadIdx.x;
    const int lane = tid & 63;
    const int wid  = tid >> 6;                       // 0 or 1

    // ---- mask storage sniff (per-thread, wave-uniform, no barrier) ----
    int mode;
    {
        const int*   wi = (const int*)maskraw;
        const float* wf = (const float*)maskraw;
        bool okInt = true, okF = true;
        #pragma unroll 4
        for (int k = 0; k < 32; ++k) {
            int v = wi[k];
            if (v != 0 && v != 1) okInt = false;
            float fv = wf[k];
            if (fv != 0.0f && fv != 1.0f) okF = false;
        }
        mode = okInt ? 0 : (okF ? 1 : 2);
    }

    // ---- load 8 elements / thread; classify; zero histogram ----
    float xv[E]; int f[E];
    #pragma unroll
    for (int e = 0; e < E; ++e) {
        const int i = tid * E + e;
        const int g = i * Cn + c;
        xv[e] = x[g];
        int t = tgt[g];
        bool m;
        if (mode == 0)      m = ((const int*)maskraw)[g] != 0;
        else if (mode == 1) m = ((const float*)maskraw)[g] != 0.0f;
        else                m = ((const unsigned char*)maskraw)[g] != 0;
        f[e] = m ? ((t == 1) ? 1 : ((t == 0) ? 2 : 3)) : 0;
    }
    #pragma unroll
    for (int q = 0; q < HPT; ++q) hist[tid * HPT + q] = 0u;

    // ---- packed (valid,neg,pos) prefix scan over element order ----
    unsigned long long local = 0;
    #pragma unroll
    for (int e = 0; e < E; ++e) local += pk3(f[e]);
    unsigned long long v = local;
    #pragma unroll
    for (int off = 1; off < 64; off <<= 1) {
        unsigned long long o = __shfl_up(v, off);
        if (lane >= off) v += o;
    }
    if (lane == 63) wtot[wid] = v;
    __syncthreads();                                 // B1: wtot + hist-zero fenced
    const unsigned long long tot = wtot[0] + wtot[1];
    unsigned long long run = ((wid == 1) ? wtot[0] : 0ull) + v - local;

    const int M = (int)(tot & 0x1FFFFF);
    const int N = (int)((tot >> 21) & 0x1FFFFF);
    const int P = (int)((tot >> 42) & 0x1FFFFF);
    const bool active = (P > 0) && (N > 0);

    // ---- r closed form, ranking write, histogram atomics, 32-bit keys ----
    int r[E];
    unsigned int kr[E];
    #pragma unroll
    for (int e = 0; e < E; ++e) {
        const int i = tid * E + e;
        const int vb = (int)(run & 0x1FFFFF);
        const int nb = (int)((run >> 21) & 0x1FFFFF);
        const int pb = (int)((run >> 42) & 0x1FFFFF);
        const int mfi = (f[e] != 0) ? 1 : 0;
        const int bse = M - mfi - 2 * vb;
        r[e] = (f[e] == 1) ? bse + 2 * nb
             : ((f[e] == 2) ? bse + 2 * pb - 2 * P : bse);
        run += pk3(f[e]);

        out[1 + i * Cn + c] = (active && f[e] != 0) ? (float)r[e] : 0.0f;

        if (f[e] == 1)      atomicAdd(&hist[(r[e] + ROFF) >> 1], 1u << 16);
        else if (f[e] == 2) atomicAdd(&hist[(r[e] + ROFF) >> 1], 1u);

        unsigned int bits = __float_as_uint(xv[e]);
        unsigned int masc = bits ^ ((bits >> 31) ? 0xFFFFFFFFu : 0x80000000u);
        unsigned int kw = ~masc;                     // descending-x sorts first
        kr[e] = (f[e] == 0) ? 0xFFFFFFFCu
                            : ((kw & 0xFFFFFFFCu) | (unsigned int)f[e]);
    }

    // ---- bitonic sort (ascending): j<=4 in-reg, j=8..256 shfl, j=512 LDS ----
    #pragma unroll
    for (int k = 2; k <= Bn; k <<= 1) {
        #pragma unroll
        for (int j = k >> 1; j > 0; j >>= 1) {
            if (j >= 512) {                          // one stage: k=1024, j=512
                #pragma unroll
                for (int e = 0; e < E; ++e) kbuf[tid * E + e] = kr[e];
                __syncthreads();                     // B2 (atomics also drained)
                const int ptid = tid ^ (j >> 3);     // thread distance 64
                #pragma unroll
                for (int e = 0; e < E; ++e) {
                    unsigned int o = kbuf[ptid * E + e];
                    const int i = tid * E + e;
                    bool keepmin = ((i & k) == 0) == ((i & j) == 0);
                    kr[e] = ((kr[e] < o) == keepmin) ? kr[e] : o;
                }
            } else if (j >= E) {                     // lane distance 1..32
                const int jl = j >> 3;
                #pragma unroll
                for (int e = 0; e < E; ++e) {
                    unsigned int o = __shfl_xor(kr[e], jl);
                    const int i = tid * E + e;
                    bool keepmin = ((i & k) == 0) == ((i & j) == 0);
                    kr[e] = ((kr[e] < o) == keepmin) ? kr[e] : o;
                }
            } else {                                 // j in {1,2,4}: within thread
                #pragma unroll
                for (int e = 0; e < E; ++e) {
                    if ((e & j) == 0) {
                        const int e2 = e | j;
                        bool up = (((tid * E + e) & k) == 0);
                        unsigned int a = kr[e], b = kr[e2];
                        bool sw = ((a > b) == up);
                        kr[e]  = sw ? b : a;
                        kr[e2] = sw ? a : b;
                    }
                }
            }
        }
    }
    // kr[e] = key at sorted position i = tid*E+e (valids desc-x first, invalids last)

    // ---- histogram inclusive scan (16 bins/thread) + AP pos-indicator scan ----
    unsigned int h[HPT]; unsigned int hl = 0;
    #pragma unroll
    for (int q = 0; q < HPT; ++q) { h[q] = hist[tid * HPT + q]; hl += h[q]; }
    unsigned int hv = hl;
    #pragma unroll
    for (int off = 1; off < 64; off <<= 1) {
        unsigned int o = __shfl_up(hv, off);
        if (lane >= off) hv += o;
    }
    if (lane == 63) hwt[wid] = hv;

    int pl = 0;
    #pragma unroll
    for (int e = 0; e < E; ++e) pl += ((kr[e] & 3u) == 1u) ? 1 : 0;
    int pv = pl;
    #pragma unroll
    for (int off = 1; off < 64; off <<= 1) {
        int o = __shfl_up(pv, off);
        if (lane >= off) pv += o;
    }
    if (lane == 63) iwt[wid] = pv;
    __syncthreads();                                 // B3: hwt + iwt ready

    unsigned int hrun = ((wid == 1) ? hwt[0] : 0u) + hv - hl;
    #pragma unroll
    for (int q = 0; q < HPT; ++q) { hrun += h[q]; hist[tid * HPT + q] = hrun; }

    float S_ap = 0.0f;
    int prun = ((wid == 1) ? iwt[0] : 0) + pv - pl;
    #pragma unroll
    for (int e = 0; e < E; ++e) {
        int pe = ((kr[e] & 3u) == 1u) ? 1 : 0;
        prun += pe;
        if (pe) S_ap += (float)prun / (float)(tid * E + e + 1);
    }
    __syncthreads();                                 // B4: inclusive hist visible

    // ---- per-element pairwise terms via histogram lookup ----
    float S_t1 = 0.0f, S_t2 = 0.0f, S_px = 0.0f, S_nx = 0.0f;
    #pragma unroll
    for (int e = 0; e < E; ++e) {
        if (f[e] == 1) {
            int rb = (r[e] + ROFF) >> 1;             // >= 1024, rb-1 safe
            int cnt = (int)(hist[rb - 1] & 0xFFFFu); // negs with r' < r
            S_t1 += xv[e] * (2.0f * (float)cnt - (float)N);
            S_px += xv[e];
        } else if (f[e] == 2) {
            int rb = (r[e] + ROFF) >> 1;
            int cnt = P - (int)(hist[rb] >> 16);     // pos with r' > r
            S_t2 += xv[e] * (2.0f * (float)cnt - (float)P);
            S_nx += xv[e];
        }
    }

    // ---- per-wave reduction + atomic epilogue (loss linear in wave sums) ----
    #pragma unroll
    for (int off = 32; off > 0; off >>= 1) {
        S_ap += __shfl_down(S_ap, off);
        S_t1 += __shfl_down(S_t1, off);
        S_t2 += __shfl_down(S_t2, off);
        S_px += __shfl_down(S_px, off);
        S_nx += __shfl_down(S_nx, off);
    }
    if (lane == 0 && active) {
        float Pf = (float)P, Nf = (float)N;
        float denom = Pf * Nf + 1e-8f;
        float contrib = (wid == 0 ? 1.0f : 0.0f)
                      - S_ap / (Pf + 1e-8f)
                      + (S_t1 - S_t2) / denom
                      - (Nf * S_px - Pf * S_nx) / denom;
        atomicAdd(out, contrib * (1.0f / (float)Cn));
    }
}

extern "C" void kernel_launch(void* const* d_in, const int* in_sizes, int n_in,
                              void* d_out, int out_size, void* d_ws, size_t ws_size,
                              hipStream_t stream) {
    const float* x   = (const float*)d_in[0];
    const int*   tgt = (const int*)d_in[1];
    const void*  msk = d_in[2];
    float* out = (float*)d_out;

    hipMemsetAsync(out, 0, sizeof(float), stream);   // zero the loss accumulator
    hipLaunchKernelGGL(map_loss_kernel, dim3(Cn), dim3(TPB), 0, stream,
                       x, tgt, msk, out);
}